// Round 1
// baseline (2977.248 us; speedup 1.0000x reference)
//
#include <hip/hip_runtime.h>

#define NN 100000
#define NE 1600000
#define DD 128
#define BN_EPS 1e-5f
#define TM 32   // rows per block in the GEMM kernel (100000 = 3125 * 32, exact)

// ---------------------------------------------------------------------------
// Phase 1: scatter-add  aggr[dst] += w * x[src]
// One thread handles one (edge, 4-float chunk): 32 chunks per edge.
// ---------------------------------------------------------------------------
__global__ __launch_bounds__(256) void scatter_kernel(
    const float* __restrict__ x, const int* __restrict__ ei,
    const float* __restrict__ ew, float* __restrict__ aggr) {
  int gid = blockIdx.x * 256 + threadIdx.x;
  const int total = NE * 32;                 // 51.2M work items
  if (gid >= total) return;
  int e = gid >> 5;                          // edge index
  int c = (gid & 31) << 2;                   // column base (0,4,...,124)
  int src = ei[e];                           // edge_index[0][e]
  int dst = ei[NE + e];                      // edge_index[1][e]
  float w = ew[e];
  float4 xv = *reinterpret_cast<const float4*>(x + (size_t)src * DD + c);
  float* ap = aggr + (size_t)dst * DD + c;
  atomicAdd(ap + 0, xv.x * w);
  atomicAdd(ap + 1, xv.y * w);
  atomicAdd(ap + 2, xv.z * w);
  atomicAdd(ap + 3, xv.w * w);
}

// ---------------------------------------------------------------------------
// Phase 2: h = aggr @ W_rel + b_rel + x @ W_root  (written to d_out)
// Fused BN statistics: per-column sum and sum-of-squares via LDS + global atomics.
// Block: 256 threads, 32 rows x 128 cols tile. Thread (t&31)*4 = col base,
// t>>5 = row group (4 rows each). 16 outputs/thread, 4096 FMAs/thread.
// W matrices stream from L2 (128 KB total, fully cached).
// ---------------------------------------------------------------------------
__global__ __launch_bounds__(256) void gemm_bn_stats_kernel(
    const float* __restrict__ aggr, const float* __restrict__ x,
    const float* __restrict__ Wrel, const float* __restrict__ Wroot,
    const float* __restrict__ brel, float* __restrict__ h,
    float* __restrict__ gsum, float* __restrict__ gsq) {
  __shared__ float Als[TM][DD];   // 16 KB
  __shared__ float Xls[TM][DD];   // 16 KB
  __shared__ float s_sum[DD];
  __shared__ float s_sq[DD];

  const int t = threadIdx.x;
  const int row0 = blockIdx.x * TM;

  if (t < DD) { s_sum[t] = 0.f; s_sq[t] = 0.f; }

  // Stage A tiles (float4 loads, coalesced)
  for (int i = t; i < TM * (DD / 4); i += 256) {
    int r = i >> 5;            // row within tile
    int gr = row0 + r;
    float4 av = make_float4(0.f, 0.f, 0.f, 0.f), xv = av;
    if (gr < NN) {
      av = reinterpret_cast<const float4*>(aggr)[(size_t)gr * 32 + (i & 31)];
      xv = reinterpret_cast<const float4*>(x)[(size_t)gr * 32 + (i & 31)];
    }
    reinterpret_cast<float4*>(&Als[0][0])[i] = av;
    reinterpret_cast<float4*>(&Xls[0][0])[i] = xv;
  }
  __syncthreads();

  const int c4 = (t & 31) << 2;   // col base
  const int rg = t >> 5;          // row group 0..7

  float acc[4][4];
  #pragma unroll
  for (int i = 0; i < 4; i++)
    #pragma unroll
    for (int j = 0; j < 4; j++) acc[i][j] = 0.f;

  // GEMM 1: aggr @ W_rel
  #pragma unroll 2
  for (int k = 0; k < DD; k += 4) {
    float4 w0 = *reinterpret_cast<const float4*>(Wrel + (k + 0) * DD + c4);
    float4 w1 = *reinterpret_cast<const float4*>(Wrel + (k + 1) * DD + c4);
    float4 w2 = *reinterpret_cast<const float4*>(Wrel + (k + 2) * DD + c4);
    float4 w3 = *reinterpret_cast<const float4*>(Wrel + (k + 3) * DD + c4);
    #pragma unroll
    for (int i = 0; i < 4; i++) {
      float4 a = *reinterpret_cast<const float4*>(&Als[rg * 4 + i][k]);
      acc[i][0] += a.x * w0.x + a.y * w1.x + a.z * w2.x + a.w * w3.x;
      acc[i][1] += a.x * w0.y + a.y * w1.y + a.z * w2.y + a.w * w3.y;
      acc[i][2] += a.x * w0.z + a.y * w1.z + a.z * w2.z + a.w * w3.z;
      acc[i][3] += a.x * w0.w + a.y * w1.w + a.z * w2.w + a.w * w3.w;
    }
  }
  // GEMM 2: x @ W_root
  #pragma unroll 2
  for (int k = 0; k < DD; k += 4) {
    float4 w0 = *reinterpret_cast<const float4*>(Wroot + (k + 0) * DD + c4);
    float4 w1 = *reinterpret_cast<const float4*>(Wroot + (k + 1) * DD + c4);
    float4 w2 = *reinterpret_cast<const float4*>(Wroot + (k + 2) * DD + c4);
    float4 w3 = *reinterpret_cast<const float4*>(Wroot + (k + 3) * DD + c4);
    #pragma unroll
    for (int i = 0; i < 4; i++) {
      float4 a = *reinterpret_cast<const float4*>(&Xls[rg * 4 + i][k]);
      acc[i][0] += a.x * w0.x + a.y * w1.x + a.z * w2.x + a.w * w3.x;
      acc[i][1] += a.x * w0.y + a.y * w1.y + a.z * w2.y + a.w * w3.y;
      acc[i][2] += a.x * w0.z + a.y * w1.z + a.z * w2.z + a.w * w3.z;
      acc[i][3] += a.x * w0.w + a.y * w1.w + a.z * w2.w + a.w * w3.w;
    }
  }

  // Epilogue: + b_rel, store h, accumulate BN statistics
  float4 b4 = *reinterpret_cast<const float4*>(brel + c4);
  float ps0 = 0.f, ps1 = 0.f, ps2 = 0.f, ps3 = 0.f;
  float pq0 = 0.f, pq1 = 0.f, pq2 = 0.f, pq3 = 0.f;
  #pragma unroll
  for (int i = 0; i < 4; i++) {
    int gr = row0 + rg * 4 + i;
    if (gr < NN) {
      float v0 = acc[i][0] + b4.x;
      float v1 = acc[i][1] + b4.y;
      float v2 = acc[i][2] + b4.z;
      float v3 = acc[i][3] + b4.w;
      reinterpret_cast<float4*>(h)[(size_t)gr * 32 + (c4 >> 2)] =
          make_float4(v0, v1, v2, v3);
      ps0 += v0; ps1 += v1; ps2 += v2; ps3 += v3;
      pq0 += v0 * v0; pq1 += v1 * v1; pq2 += v2 * v2; pq3 += v3 * v3;
    }
  }
  atomicAdd(&s_sum[c4 + 0], ps0);
  atomicAdd(&s_sum[c4 + 1], ps1);
  atomicAdd(&s_sum[c4 + 2], ps2);
  atomicAdd(&s_sum[c4 + 3], ps3);
  atomicAdd(&s_sq[c4 + 0], pq0);
  atomicAdd(&s_sq[c4 + 1], pq1);
  atomicAdd(&s_sq[c4 + 2], pq2);
  atomicAdd(&s_sq[c4 + 3], pq3);
  __syncthreads();
  if (t < DD) {
    atomicAdd(&gsum[t], s_sum[t]);
    atomicAdd(&gsq[t], s_sq[t]);
  }
}

// ---------------------------------------------------------------------------
// Phase 3: out = relu((h - mean) * rsqrt(var + eps) * gamma + beta) + x
// h lives in d_out; normalized in place. Pure streaming, float4.
// ---------------------------------------------------------------------------
__global__ __launch_bounds__(256) void bn_relu_res_kernel(
    const float* __restrict__ x, const float* __restrict__ gamma,
    const float* __restrict__ beta, const float* __restrict__ gsum,
    const float* __restrict__ gsq, float* __restrict__ out) {
  __shared__ float sc[DD];
  __shared__ float sh[DD];
  const int t = threadIdx.x;
  if (t < DD) {
    float mean = gsum[t] * (1.f / NN);
    float var = gsq[t] * (1.f / NN) - mean * mean;
    float rstd = rsqrtf(var + BN_EPS);
    float s = gamma[t] * rstd;
    sc[t] = s;
    sh[t] = beta[t] - mean * s;
  }
  __syncthreads();
  const int total4 = NN * DD / 4;   // 3.2M float4
  for (int i = blockIdx.x * 256 + t; i < total4; i += gridDim.x * 256) {
    float4 h4 = reinterpret_cast<const float4*>(out)[i];
    float4 x4 = reinterpret_cast<const float4*>(x)[i];
    int c = (i & 31) << 2;
    float4 o;
    o.x = fmaxf(h4.x * sc[c + 0] + sh[c + 0], 0.f) + x4.x;
    o.y = fmaxf(h4.y * sc[c + 1] + sh[c + 1], 0.f) + x4.y;
    o.z = fmaxf(h4.z * sc[c + 2] + sh[c + 2], 0.f) + x4.z;
    o.w = fmaxf(h4.w * sc[c + 3] + sh[c + 3], 0.f) + x4.w;
    reinterpret_cast<float4*>(out)[i] = o;
  }
}

// ---------------------------------------------------------------------------
extern "C" void kernel_launch(void* const* d_in, const int* in_sizes, int n_in,
                              void* d_out, int out_size, void* d_ws, size_t ws_size,
                              hipStream_t stream) {
  const float* x     = (const float*)d_in[0];
  const int*   ei    = (const int*)d_in[1];
  const float* ew    = (const float*)d_in[2];
  const float* Wrel  = (const float*)d_in[3];
  const float* brel  = (const float*)d_in[4];
  const float* Wroot = (const float*)d_in[5];
  const float* gamma = (const float*)d_in[6];
  const float* beta  = (const float*)d_in[7];
  float* out = (float*)d_out;

  // Workspace layout: aggr [NN*DD] | gsum [DD] | gsq [DD]
  float* aggr = (float*)d_ws;
  float* gsum = aggr + (size_t)NN * DD;
  float* gsq  = gsum + DD;

  hipMemsetAsync(d_ws, 0, (size_t)NN * DD * sizeof(float) + 2 * DD * sizeof(float),
                 stream);

  {
    const int total = NE * 32;
    const int blocks = (total + 255) / 256;
    scatter_kernel<<<blocks, 256, 0, stream>>>(x, ei, ew, aggr);
  }
  {
    const int blocks = (NN + TM - 1) / TM;   // 3125
    gemm_bn_stats_kernel<<<blocks, 256, 0, stream>>>(aggr, x, Wrel, Wroot, brel,
                                                     out, gsum, gsq);
  }
  bn_relu_res_kernel<<<2048, 256, 0, stream>>>(x, gamma, beta, gsum, gsq, out);
}

// Round 3
// 827.679 us; speedup vs baseline: 3.5971x; 3.5971x over previous
//
#include <hip/hip_runtime.h>

#define NN 100000
#define NE 1600000
#define DD 128
#define BN_EPS 1e-5f
#define TM 32   // rows per block in the GEMM kernel (100000 = 3125 * 32, exact)

// ---------------------------------------------------------------------------
// Phase 1a: histogram of dst degrees
// ---------------------------------------------------------------------------
__global__ __launch_bounds__(256) void hist_kernel(
    const int* __restrict__ ei, int* __restrict__ deg) {
  int e = blockIdx.x * 256 + threadIdx.x;
  if (e >= NE) return;
  atomicAdd(&deg[ei[NE + e]], 1);
}

// ---------------------------------------------------------------------------
// Phase 1b: exclusive prefix sum of deg -> offs and cursor (single block)
// ---------------------------------------------------------------------------
__global__ __launch_bounds__(1024) void scan_kernel(
    const int* __restrict__ deg, int* __restrict__ offs,
    int* __restrict__ cursor) {
  __shared__ int part[1024];
  const int CH = (NN + 1023) / 1024;   // 98
  int t = threadIdx.x;
  int lo = t * CH, hi = min(lo + CH, NN);
  int s = 0;
  for (int i = lo; i < hi; ++i) s += deg[i];
  part[t] = s;
  __syncthreads();
  // Hillis-Steele inclusive scan over 1024 partials
  for (int d = 1; d < 1024; d <<= 1) {
    int v = (t >= d) ? part[t - d] : 0;
    __syncthreads();
    part[t] += v;
    __syncthreads();
  }
  int run = (t == 0) ? 0 : part[t - 1];
  for (int i = lo; i < hi; ++i) {
    int v = deg[i];
    offs[i] = run;
    cursor[i] = run;
    run += v;
  }
}

// ---------------------------------------------------------------------------
// Phase 1c: bucket edges by dst: sorted[pos] = (src, weight)
// ---------------------------------------------------------------------------
__global__ __launch_bounds__(256) void bucket_kernel(
    const int* __restrict__ ei, const float* __restrict__ ew,
    int* __restrict__ cursor, int2* __restrict__ sorted) {
  int e = blockIdx.x * 256 + threadIdx.x;
  if (e >= NE) return;
  int src = ei[e];
  int dst = ei[NE + e];
  float w = ew[e];
  int pos = atomicAdd(&cursor[dst], 1);
  sorted[pos] = make_int2(src, __float_as_int(w));
}

// ---------------------------------------------------------------------------
// Phase 1d: gather-aggregate. One wave (64 lanes) per node; lane holds 2 cols.
// aggr row = sum over incoming edges of w * x[src]. Single write, no atomics.
// After bucketing, cursor[n] == offs[n] + deg[n] == end of bucket n.
// ---------------------------------------------------------------------------
__global__ __launch_bounds__(256) void aggregate_kernel(
    const float* __restrict__ x, const int2* __restrict__ sorted,
    const int* __restrict__ offs, const int* __restrict__ cursor,
    float* __restrict__ aggr) {
  int wid = (blockIdx.x * 256 + threadIdx.x) >> 6;   // wave id == node id
  int lane = threadIdx.x & 63;
  if (wid >= NN) return;
  int s = offs[wid];
  int e = cursor[wid];
  const float2* xp = reinterpret_cast<const float2*>(x);
  float2 acc = make_float2(0.f, 0.f);
  int i = s;
  // unroll-2 for a little ILP; TLP (100k waves) hides the rest
  for (; i + 2 <= e; i += 2) {
    int2 m0 = sorted[i];
    int2 m1 = sorted[i + 1];
    float w0 = __int_as_float(m0.y);
    float w1 = __int_as_float(m1.y);
    float2 v0 = xp[(size_t)m0.x * 64 + lane];
    float2 v1 = xp[(size_t)m1.x * 64 + lane];
    acc.x += w0 * v0.x + w1 * v1.x;
    acc.y += w0 * v0.y + w1 * v1.y;
  }
  if (i < e) {
    int2 m0 = sorted[i];
    float w0 = __int_as_float(m0.y);
    float2 v0 = xp[(size_t)m0.x * 64 + lane];
    acc.x += w0 * v0.x;
    acc.y += w0 * v0.y;
  }
  reinterpret_cast<float2*>(aggr)[(size_t)wid * 64 + lane] = acc;
}

// ---------------------------------------------------------------------------
// Phase 2: h = aggr @ W_rel + b_rel + x @ W_root  (aggr and h both in d_out;
// in-place is safe: each block stages its 32 rows into LDS before writing them,
// and no other block touches those rows.)
// Fused BN statistics via LDS + global atomics.
// ---------------------------------------------------------------------------
__global__ __launch_bounds__(256) void gemm_bn_stats_kernel(
    const float* __restrict__ aggr, const float* __restrict__ x,
    const float* __restrict__ Wrel, const float* __restrict__ Wroot,
    const float* __restrict__ brel, float* __restrict__ h,
    float* __restrict__ gsum, float* __restrict__ gsq) {
  __shared__ float Als[TM][DD];   // 16 KB
  __shared__ float Xls[TM][DD];   // 16 KB
  __shared__ float s_sum[DD];
  __shared__ float s_sq[DD];

  const int t = threadIdx.x;
  const int row0 = blockIdx.x * TM;

  if (t < DD) { s_sum[t] = 0.f; s_sq[t] = 0.f; }

  for (int i = t; i < TM * (DD / 4); i += 256) {
    int r = i >> 5;
    int gr = row0 + r;
    float4 av = make_float4(0.f, 0.f, 0.f, 0.f), xv = av;
    if (gr < NN) {
      av = reinterpret_cast<const float4*>(aggr)[(size_t)gr * 32 + (i & 31)];
      xv = reinterpret_cast<const float4*>(x)[(size_t)gr * 32 + (i & 31)];
    }
    reinterpret_cast<float4*>(&Als[0][0])[i] = av;
    reinterpret_cast<float4*>(&Xls[0][0])[i] = xv;
  }
  __syncthreads();

  const int c4 = (t & 31) << 2;
  const int rg = t >> 5;

  float acc[4][4];
  #pragma unroll
  for (int i = 0; i < 4; i++)
    #pragma unroll
    for (int j = 0; j < 4; j++) acc[i][j] = 0.f;

  #pragma unroll 2
  for (int k = 0; k < DD; k += 4) {
    float4 w0 = *reinterpret_cast<const float4*>(Wrel + (k + 0) * DD + c4);
    float4 w1 = *reinterpret_cast<const float4*>(Wrel + (k + 1) * DD + c4);
    float4 w2 = *reinterpret_cast<const float4*>(Wrel + (k + 2) * DD + c4);
    float4 w3 = *reinterpret_cast<const float4*>(Wrel + (k + 3) * DD + c4);
    #pragma unroll
    for (int i = 0; i < 4; i++) {
      float4 a = *reinterpret_cast<const float4*>(&Als[rg * 4 + i][k]);
      acc[i][0] += a.x * w0.x + a.y * w1.x + a.z * w2.x + a.w * w3.x;
      acc[i][1] += a.x * w0.y + a.y * w1.y + a.z * w2.y + a.w * w3.y;
      acc[i][2] += a.x * w0.z + a.y * w1.z + a.z * w2.z + a.w * w3.z;
      acc[i][3] += a.x * w0.w + a.y * w1.w + a.z * w2.w + a.w * w3.w;
    }
  }
  #pragma unroll 2
  for (int k = 0; k < DD; k += 4) {
    float4 w0 = *reinterpret_cast<const float4*>(Wroot + (k + 0) * DD + c4);
    float4 w1 = *reinterpret_cast<const float4*>(Wroot + (k + 1) * DD + c4);
    float4 w2 = *reinterpret_cast<const float4*>(Wroot + (k + 2) * DD + c4);
    float4 w3 = *reinterpret_cast<const float4*>(Wroot + (k + 3) * DD + c4);
    #pragma unroll
    for (int i = 0; i < 4; i++) {
      float4 a = *reinterpret_cast<const float4*>(&Xls[rg * 4 + i][k]);
      acc[i][0] += a.x * w0.x + a.y * w1.x + a.z * w2.x + a.w * w3.x;
      acc[i][1] += a.x * w0.y + a.y * w1.y + a.z * w2.y + a.w * w3.y;
      acc[i][2] += a.x * w0.z + a.y * w1.z + a.z * w2.z + a.w * w3.z;
      acc[i][3] += a.x * w0.w + a.y * w1.w + a.z * w2.w + a.w * w3.w;
    }
  }

  float4 b4 = *reinterpret_cast<const float4*>(brel + c4);
  float ps0 = 0.f, ps1 = 0.f, ps2 = 0.f, ps3 = 0.f;
  float pq0 = 0.f, pq1 = 0.f, pq2 = 0.f, pq3 = 0.f;
  #pragma unroll
  for (int i = 0; i < 4; i++) {
    int gr = row0 + rg * 4 + i;
    if (gr < NN) {
      float v0 = acc[i][0] + b4.x;
      float v1 = acc[i][1] + b4.y;
      float v2 = acc[i][2] + b4.z;
      float v3 = acc[i][3] + b4.w;
      reinterpret_cast<float4*>(h)[(size_t)gr * 32 + (c4 >> 2)] =
          make_float4(v0, v1, v2, v3);
      ps0 += v0; ps1 += v1; ps2 += v2; ps3 += v3;
      pq0 += v0 * v0; pq1 += v1 * v1; pq2 += v2 * v2; pq3 += v3 * v3;
    }
  }
  atomicAdd(&s_sum[c4 + 0], ps0);
  atomicAdd(&s_sum[c4 + 1], ps1);
  atomicAdd(&s_sum[c4 + 2], ps2);
  atomicAdd(&s_sum[c4 + 3], ps3);
  atomicAdd(&s_sq[c4 + 0], pq0);
  atomicAdd(&s_sq[c4 + 1], pq1);
  atomicAdd(&s_sq[c4 + 2], pq2);
  atomicAdd(&s_sq[c4 + 3], pq3);
  __syncthreads();
  if (t < DD) {
    atomicAdd(&gsum[t], s_sum[t]);
    atomicAdd(&gsq[t], s_sq[t]);
  }
}

// ---------------------------------------------------------------------------
// Phase 3: out = relu((h - mean) * rsqrt(var + eps) * gamma + beta) + x
// ---------------------------------------------------------------------------
__global__ __launch_bounds__(256) void bn_relu_res_kernel(
    const float* __restrict__ x, const float* __restrict__ gamma,
    const float* __restrict__ beta, const float* __restrict__ gsum,
    const float* __restrict__ gsq, float* __restrict__ out) {
  __shared__ float sc[DD];
  __shared__ float sh[DD];
  const int t = threadIdx.x;
  if (t < DD) {
    float mean = gsum[t] * (1.f / NN);
    float var = gsq[t] * (1.f / NN) - mean * mean;
    float rstd = rsqrtf(var + BN_EPS);
    float s = gamma[t] * rstd;
    sc[t] = s;
    sh[t] = beta[t] - mean * s;
  }
  __syncthreads();
  const int total4 = NN * DD / 4;
  for (int i = blockIdx.x * 256 + t; i < total4; i += gridDim.x * 256) {
    float4 h4 = reinterpret_cast<const float4*>(out)[i];
    float4 x4 = reinterpret_cast<const float4*>(x)[i];
    int c = (i & 31) << 2;
    float4 o;
    o.x = fmaxf(h4.x * sc[c + 0] + sh[c + 0], 0.f) + x4.x;
    o.y = fmaxf(h4.y * sc[c + 1] + sh[c + 1], 0.f) + x4.y;
    o.z = fmaxf(h4.z * sc[c + 2] + sh[c + 2], 0.f) + x4.z;
    o.w = fmaxf(h4.w * sc[c + 3] + sh[c + 3], 0.f) + x4.w;
    reinterpret_cast<float4*>(out)[i] = o;
  }
}

// ---------------------------------------------------------------------------
extern "C" void kernel_launch(void* const* d_in, const int* in_sizes, int n_in,
                              void* d_out, int out_size, void* d_ws, size_t ws_size,
                              hipStream_t stream) {
  const float* x     = (const float*)d_in[0];
  const int*   ei    = (const int*)d_in[1];
  const float* ew    = (const float*)d_in[2];
  const float* Wrel  = (const float*)d_in[3];
  const float* brel  = (const float*)d_in[4];
  const float* Wroot = (const float*)d_in[5];
  const float* gamma = (const float*)d_in[6];
  const float* beta  = (const float*)d_in[7];
  float* out = (float*)d_out;

  // ws layout (ints unless noted): deg[NN] | gsum[DD] f32 | gsq[DD] f32 |
  //                                offs[NN] | cursor[NN] | sorted[NE] int2
  int*   deg    = (int*)d_ws;
  float* gsum   = (float*)(deg + NN);
  float* gsq    = gsum + DD;
  int*   offs   = (int*)(gsq + DD);
  int*   cursor = offs + NN;
  int2*  sorted = (int2*)(cursor + NN);   // offset 300256 ints, 8B-aligned

  // zero: deg + gsum + gsq (contiguous head of ws)
  hipMemsetAsync(d_ws, 0, (size_t)(NN + 2 * DD) * sizeof(int), stream);

  // aggr lives in d_out; GEMM consumes it in place.
  float* aggr = out;

  const int eblocks = (NE + 255) / 256;   // 6250
  hist_kernel<<<eblocks, 256, 0, stream>>>(ei, deg);
  scan_kernel<<<1, 1024, 0, stream>>>(deg, offs, cursor);
  bucket_kernel<<<eblocks, 256, 0, stream>>>(ei, ew, cursor, sorted);
  {
    const int waves = NN;                        // one wave per node
    const int blocks = (waves * 64 + 255) / 256; // 25000
    aggregate_kernel<<<blocks, 256, 0, stream>>>(x, sorted, offs, cursor, aggr);
  }
  gemm_bn_stats_kernel<<<(NN + TM - 1) / TM, 256, 0, stream>>>(
      aggr, x, Wrel, Wroot, brel, out, gsum, gsq);
  bn_relu_res_kernel<<<2048, 256, 0, stream>>>(x, gamma, beta, gsum, gsq, out);
}

// Round 6
// 597.734 us; speedup vs baseline: 4.9809x; 1.3847x over previous
//
#include <hip/hip_runtime.h>

#define NN 100000
#define NE 1600000
#define DD 128
#define BN_EPS 1e-5f
#define TM 32        // rows per block in the GEMM kernel
#define NB 391       // scan blocks: 391*256 = 100096 >= NN

// ---------------------------------------------------------------------------
// Phase 1a: histogram of dst degrees
// ---------------------------------------------------------------------------
__global__ __launch_bounds__(256) void hist_kernel(
    const int* __restrict__ ei, int* __restrict__ deg) {
  int e = blockIdx.x * 256 + threadIdx.x;
  if (e >= NE) return;
  atomicAdd(&deg[ei[NE + e]], 1);
}

// ---------------------------------------------------------------------------
// Phase 1b: device-wide exclusive scan of deg, 3 tiny kernels.
// ---------------------------------------------------------------------------
__global__ __launch_bounds__(256) void scan_part_kernel(
    const int* __restrict__ deg, int* __restrict__ bsum) {
  __shared__ int sc[256];
  int t = threadIdx.x;
  int i = blockIdx.x * 256 + t;
  int v = (i < NN) ? deg[i] : 0;
  sc[t] = v;
  __syncthreads();
  #pragma unroll
  for (int d = 1; d < 256; d <<= 1) {
    int u = (t >= d) ? sc[t - d] : 0;
    __syncthreads();
    sc[t] += u;
    __syncthreads();
  }
  if (t == 255) bsum[blockIdx.x] = sc[255];
}

__global__ __launch_bounds__(512) void scan_block_kernel(
    int* __restrict__ bsum, int* __restrict__ bofs) {
  __shared__ int sc[512];
  int t = threadIdx.x;
  int v = (t < NB) ? bsum[t] : 0;
  sc[t] = v;
  __syncthreads();
  #pragma unroll
  for (int d = 1; d < 512; d <<= 1) {
    int u = (t >= d) ? sc[t - d] : 0;
    __syncthreads();
    sc[t] += u;
    __syncthreads();
  }
  if (t < NB) bofs[t] = sc[t] - v;   // exclusive
}

__global__ __launch_bounds__(256) void scan_write_kernel(
    const int* __restrict__ deg, const int* __restrict__ bofs,
    int* __restrict__ offs, int* __restrict__ cursor) {
  __shared__ int sc[256];
  int t = threadIdx.x;
  int i = blockIdx.x * 256 + t;
  int v = (i < NN) ? deg[i] : 0;
  sc[t] = v;
  __syncthreads();
  #pragma unroll
  for (int d = 1; d < 256; d <<= 1) {
    int u = (t >= d) ? sc[t - d] : 0;
    __syncthreads();
    sc[t] += u;
    __syncthreads();
  }
  if (i < NN) {
    int excl = sc[t] - v + bofs[blockIdx.x];
    offs[i] = excl;
    cursor[i] = excl;
  }
}

// ---------------------------------------------------------------------------
// Phase 1c: bucket edges by dst: sorted[pos] = (src, weight)
// ---------------------------------------------------------------------------
__global__ __launch_bounds__(256) void bucket_kernel(
    const int* __restrict__ ei, const float* __restrict__ ew,
    int* __restrict__ cursor, int2* __restrict__ sorted) {
  int e = blockIdx.x * 256 + threadIdx.x;
  if (e >= NE) return;
  int src = ei[e];
  int dst = ei[NE + e];
  float w = ew[e];
  int pos = atomicAdd(&cursor[dst], 1);
  sorted[pos] = make_int2(src, __float_as_int(w));
}

// ---------------------------------------------------------------------------
// Phase 1d: gather-aggregate. One wave (64 lanes) per node.
// Lanes 0-31 process even-position edges, lanes 32-63 odd-position edges;
// each lane holds 4 columns (float4, 16 B = coalescing sweet spot). The two
// half-wave partial sums are combined with 4 __shfl_xor(…,32) per node.
// After bucketing, cursor[n] == offs[n] + deg[n] == end of bucket n.
// ---------------------------------------------------------------------------
__global__ __launch_bounds__(256) void aggregate_kernel(
    const float* __restrict__ x, const int2* __restrict__ sorted,
    const int* __restrict__ offs, const int* __restrict__ cursor,
    float* __restrict__ aggr) {
  int wid = (blockIdx.x * 256 + threadIdx.x) >> 6;   // wave id == node id
  int lane = threadIdx.x & 63;
  int half = lane >> 5;        // 0: even edges, 1: odd edges
  int l32 = lane & 31;         // column group: cols l32*4 .. l32*4+3
  if (wid >= NN) return;
  int s = offs[wid];
  int e = cursor[wid];
  const float4* xp = reinterpret_cast<const float4*>(x);
  float4 acc = make_float4(0.f, 0.f, 0.f, 0.f);
  for (int i = s + half; i < e; i += 2) {
    int2 m = sorted[i];
    float w = __int_as_float(m.y);
    float4 v = xp[(size_t)m.x * 32 + l32];
    acc.x += w * v.x;
    acc.y += w * v.y;
    acc.z += w * v.z;
    acc.w += w * v.w;
  }
  // combine the two halves (lane ^ 32)
  acc.x += __shfl_xor(acc.x, 32, 64);
  acc.y += __shfl_xor(acc.y, 32, 64);
  acc.z += __shfl_xor(acc.z, 32, 64);
  acc.w += __shfl_xor(acc.w, 32, 64);
  if (half == 0) {
    reinterpret_cast<float4*>(aggr)[(size_t)wid * 32 + l32] = acc;
  }
}

// ---------------------------------------------------------------------------
// Phase 2: h = aggr @ W_rel + b_rel + x @ W_root  (aggr and h both in d_out;
// in-place safe: each block stages its 32 rows into LDS before writing them.)
// Fused BN statistics via LDS + global atomics.
// ---------------------------------------------------------------------------
__global__ __launch_bounds__(256) void gemm_bn_stats_kernel(
    const float* __restrict__ aggr, const float* __restrict__ x,
    const float* __restrict__ Wrel, const float* __restrict__ Wroot,
    const float* __restrict__ brel, float* __restrict__ h,
    float* __restrict__ gsum, float* __restrict__ gsq) {
  __shared__ float Als[TM][DD];   // 16 KB
  __shared__ float Xls[TM][DD];   // 16 KB
  __shared__ float s_sum[DD];
  __shared__ float s_sq[DD];

  const int t = threadIdx.x;
  const int row0 = blockIdx.x * TM;

  if (t < DD) { s_sum[t] = 0.f; s_sq[t] = 0.f; }

  for (int i = t; i < TM * (DD / 4); i += 256) {
    int r = i >> 5;
    int gr = row0 + r;
    float4 av = make_float4(0.f, 0.f, 0.f, 0.f), xv = av;
    if (gr < NN) {
      av = reinterpret_cast<const float4*>(aggr)[(size_t)gr * 32 + (i & 31)];
      xv = reinterpret_cast<const float4*>(x)[(size_t)gr * 32 + (i & 31)];
    }
    reinterpret_cast<float4*>(&Als[0][0])[i] = av;
    reinterpret_cast<float4*>(&Xls[0][0])[i] = xv;
  }
  __syncthreads();

  const int c4 = (t & 31) << 2;
  const int rg = t >> 5;

  float acc[4][4];
  #pragma unroll
  for (int i = 0; i < 4; i++)
    #pragma unroll
    for (int j = 0; j < 4; j++) acc[i][j] = 0.f;

  #pragma unroll 2
  for (int k = 0; k < DD; k += 4) {
    float4 w0 = *reinterpret_cast<const float4*>(Wrel + (k + 0) * DD + c4);
    float4 w1 = *reinterpret_cast<const float4*>(Wrel + (k + 1) * DD + c4);
    float4 w2 = *reinterpret_cast<const float4*>(Wrel + (k + 2) * DD + c4);
    float4 w3 = *reinterpret_cast<const float4*>(Wrel + (k + 3) * DD + c4);
    #pragma unroll
    for (int i = 0; i < 4; i++) {
      float4 a = *reinterpret_cast<const float4*>(&Als[rg * 4 + i][k]);
      acc[i][0] += a.x * w0.x + a.y * w1.x + a.z * w2.x + a.w * w3.x;
      acc[i][1] += a.x * w0.y + a.y * w1.y + a.z * w2.y + a.w * w3.y;
      acc[i][2] += a.x * w0.z + a.y * w1.z + a.z * w2.z + a.w * w3.z;
      acc[i][3] += a.x * w0.w + a.y * w1.w + a.z * w2.w + a.w * w3.w;
    }
  }
  #pragma unroll 2
  for (int k = 0; k < DD; k += 4) {
    float4 w0 = *reinterpret_cast<const float4*>(Wroot + (k + 0) * DD + c4);
    float4 w1 = *reinterpret_cast<const float4*>(Wroot + (k + 1) * DD + c4);
    float4 w2 = *reinterpret_cast<const float4*>(Wroot + (k + 2) * DD + c4);
    float4 w3 = *reinterpret_cast<const float4*>(Wroot + (k + 3) * DD + c4);
    #pragma unroll
    for (int i = 0; i < 4; i++) {
      float4 a = *reinterpret_cast<const float4*>(&Xls[rg * 4 + i][k]);
      acc[i][0] += a.x * w0.x + a.y * w1.x + a.z * w2.x + a.w * w3.x;
      acc[i][1] += a.x * w0.y + a.y * w1.y + a.z * w2.y + a.w * w3.y;
      acc[i][2] += a.x * w0.z + a.y * w1.z + a.z * w2.z + a.w * w3.z;
      acc[i][3] += a.x * w0.w + a.y * w1.w + a.z * w2.w + a.w * w3.w;
    }
  }

  float4 b4 = *reinterpret_cast<const float4*>(brel + c4);
  float ps0 = 0.f, ps1 = 0.f, ps2 = 0.f, ps3 = 0.f;
  float pq0 = 0.f, pq1 = 0.f, pq2 = 0.f, pq3 = 0.f;
  #pragma unroll
  for (int i = 0; i < 4; i++) {
    int gr = row0 + rg * 4 + i;
    if (gr < NN) {
      float v0 = acc[i][0] + b4.x;
      float v1 = acc[i][1] + b4.y;
      float v2 = acc[i][2] + b4.z;
      float v3 = acc[i][3] + b4.w;
      reinterpret_cast<float4*>(h)[(size_t)gr * 32 + (c4 >> 2)] =
          make_float4(v0, v1, v2, v3);
      ps0 += v0; ps1 += v1; ps2 += v2; ps3 += v3;
      pq0 += v0 * v0; pq1 += v1 * v1; pq2 += v2 * v2; pq3 += v3 * v3;
    }
  }
  atomicAdd(&s_sum[c4 + 0], ps0);
  atomicAdd(&s_sum[c4 + 1], ps1);
  atomicAdd(&s_sum[c4 + 2], ps2);
  atomicAdd(&s_sum[c4 + 3], ps3);
  atomicAdd(&s_sq[c4 + 0], pq0);
  atomicAdd(&s_sq[c4 + 1], pq1);
  atomicAdd(&s_sq[c4 + 2], pq2);
  atomicAdd(&s_sq[c4 + 3], pq3);
  __syncthreads();
  if (t < DD) {
    atomicAdd(&gsum[t], s_sum[t]);
    atomicAdd(&gsq[t], s_sq[t]);
  }
}

// ---------------------------------------------------------------------------
// Phase 3: out = relu((h - mean) * rsqrt(var + eps) * gamma + beta) + x
// ---------------------------------------------------------------------------
__global__ __launch_bounds__(256) void bn_relu_res_kernel(
    const float* __restrict__ x, const float* __restrict__ gamma,
    const float* __restrict__ beta, const float* __restrict__ gsum,
    const float* __restrict__ gsq, float* __restrict__ out) {
  __shared__ float sc[DD];
  __shared__ float sh[DD];
  const int t = threadIdx.x;
  if (t < DD) {
    float mean = gsum[t] * (1.f / NN);
    float var = gsq[t] * (1.f / NN) - mean * mean;
    float rstd = rsqrtf(var + BN_EPS);
    float s = gamma[t] * rstd;
    sc[t] = s;
    sh[t] = beta[t] - mean * s;
  }
  __syncthreads();
  const int total4 = NN * DD / 4;
  for (int i = blockIdx.x * 256 + t; i < total4; i += gridDim.x * 256) {
    float4 h4 = reinterpret_cast<const float4*>(out)[i];
    float4 x4 = reinterpret_cast<const float4*>(x)[i];
    int c = (i & 31) << 2;
    float4 o;
    o.x = fmaxf(h4.x * sc[c + 0] + sh[c + 0], 0.f) + x4.x;
    o.y = fmaxf(h4.y * sc[c + 1] + sh[c + 1], 0.f) + x4.y;
    o.z = fmaxf(h4.z * sc[c + 2] + sh[c + 2], 0.f) + x4.z;
    o.w = fmaxf(h4.w * sc[c + 3] + sh[c + 3], 0.f) + x4.w;
    reinterpret_cast<float4*>(out)[i] = o;
  }
}

// ---------------------------------------------------------------------------
extern "C" void kernel_launch(void* const* d_in, const int* in_sizes, int n_in,
                              void* d_out, int out_size, void* d_ws, size_t ws_size,
                              hipStream_t stream) {
  const float* x     = (const float*)d_in[0];
  const int*   ei    = (const int*)d_in[1];
  const float* ew    = (const float*)d_in[2];
  const float* Wrel  = (const float*)d_in[3];
  const float* brel  = (const float*)d_in[4];
  const float* Wroot = (const float*)d_in[5];
  const float* gamma = (const float*)d_in[6];
  const float* beta  = (const float*)d_in[7];
  float* out = (float*)d_out;

  // ws layout (ints unless noted): deg[NN] | gsum[DD] f32 | gsq[DD] f32 |
  //   offs[NN] | cursor[NN] | bsum[NB] | bofs[NB] | pad | sorted[NE] int2
  int*   deg    = (int*)d_ws;
  float* gsum   = (float*)(deg + NN);
  float* gsq    = gsum + DD;
  int*   offs   = (int*)(gsq + DD);
  int*   cursor = offs + NN;
  int*   bsum   = cursor + NN;
  int*   bofs   = bsum + NB;
  int2*  sorted = (int2*)(bofs + NB + 2);   // +2 keeps 8B alignment

  // zero: deg + gsum + gsq (contiguous head of ws)
  hipMemsetAsync(d_ws, 0, (size_t)(NN + 2 * DD) * sizeof(int), stream);

  // aggr lives in d_out; GEMM consumes it in place.
  float* aggr = out;

  const int eblocks = (NE + 255) / 256;   // 6250
  hist_kernel<<<eblocks, 256, 0, stream>>>(ei, deg);
  scan_part_kernel<<<NB, 256, 0, stream>>>(deg, bsum);
  scan_block_kernel<<<1, 512, 0, stream>>>(bsum, bofs);
  scan_write_kernel<<<NB, 256, 0, stream>>>(deg, bofs, offs, cursor);
  bucket_kernel<<<eblocks, 256, 0, stream>>>(ei, ew, cursor, sorted);
  {
    const int blocks = (NN * 64 + 255) / 256;  // 25000, one wave per node
    aggregate_kernel<<<blocks, 256, 0, stream>>>(x, sorted, offs, cursor, aggr);
  }
  gemm_bn_stats_kernel<<<(NN + TM - 1) / TM, 256, 0, stream>>>(
      aggr, x, Wrel, Wroot, brel, out, gsum, gsq);
  bn_relu_res_kernel<<<2048, 256, 0, stream>>>(x, gamma, beta, gsum, gsq, out);
}

// Round 7
// 520.408 us; speedup vs baseline: 5.7210x; 1.1486x over previous
//
#include <hip/hip_runtime.h>

#define NN 100000
#define NE 1600000
#define DD 128
#define BN_EPS 1e-5f
#define NB 391       // scan blocks: 391*256 = 100096 >= NN
#define MB 1563      // gemm blocks: 1563*64 >= NN

typedef __attribute__((ext_vector_type(8))) short short8v;
typedef __attribute__((ext_vector_type(4))) float float4v;

__device__ inline unsigned short f2bf(float f) {
  unsigned u = __float_as_uint(f);
  return (unsigned short)((u + 0x7FFF + ((u >> 16) & 1)) >> 16);  // RNE
}
__device__ inline short8v pack8(float4 a, float4 b) {
  short8v o;
  o[0] = (short)f2bf(a.x); o[1] = (short)f2bf(a.y);
  o[2] = (short)f2bf(a.z); o[3] = (short)f2bf(a.w);
  o[4] = (short)f2bf(b.x); o[5] = (short)f2bf(b.y);
  o[6] = (short)f2bf(b.z); o[7] = (short)f2bf(b.w);
  return o;
}

// ---------------------------------------------------------------------------
// Phase 1a: histogram of dst degrees
// ---------------------------------------------------------------------------
__global__ __launch_bounds__(256) void hist_kernel(
    const int* __restrict__ ei, int* __restrict__ deg) {
  int e = blockIdx.x * 256 + threadIdx.x;
  if (e >= NE) return;
  atomicAdd(&deg[ei[NE + e]], 1);
}

// ---------------------------------------------------------------------------
// Phase 1b: device-wide exclusive scan of deg, 3 tiny kernels.
// ---------------------------------------------------------------------------
__global__ __launch_bounds__(256) void scan_part_kernel(
    const int* __restrict__ deg, int* __restrict__ bsum) {
  __shared__ int sc[256];
  int t = threadIdx.x;
  int i = blockIdx.x * 256 + t;
  int v = (i < NN) ? deg[i] : 0;
  sc[t] = v;
  __syncthreads();
  #pragma unroll
  for (int d = 1; d < 256; d <<= 1) {
    int u = (t >= d) ? sc[t - d] : 0;
    __syncthreads();
    sc[t] += u;
    __syncthreads();
  }
  if (t == 255) bsum[blockIdx.x] = sc[255];
}

__global__ __launch_bounds__(512) void scan_block_kernel(
    int* __restrict__ bsum, int* __restrict__ bofs) {
  __shared__ int sc[512];
  int t = threadIdx.x;
  int v = (t < NB) ? bsum[t] : 0;
  sc[t] = v;
  __syncthreads();
  #pragma unroll
  for (int d = 1; d < 512; d <<= 1) {
    int u = (t >= d) ? sc[t - d] : 0;
    __syncthreads();
    sc[t] += u;
    __syncthreads();
  }
  if (t < NB) bofs[t] = sc[t] - v;   // exclusive
}

__global__ __launch_bounds__(256) void scan_write_kernel(
    const int* __restrict__ deg, const int* __restrict__ bofs,
    int* __restrict__ offs, int* __restrict__ cursor) {
  __shared__ int sc[256];
  int t = threadIdx.x;
  int i = blockIdx.x * 256 + t;
  int v = (i < NN) ? deg[i] : 0;
  sc[t] = v;
  __syncthreads();
  #pragma unroll
  for (int d = 1; d < 256; d <<= 1) {
    int u = (t >= d) ? sc[t - d] : 0;
    __syncthreads();
    sc[t] += u;
    __syncthreads();
  }
  if (i < NN) {
    int excl = sc[t] - v + bofs[blockIdx.x];
    offs[i] = excl;
    cursor[i] = excl;
  }
}

// ---------------------------------------------------------------------------
// Phase 1c: bucket edges by dst: sorted[pos] = (src, weight)
// ---------------------------------------------------------------------------
__global__ __launch_bounds__(256) void bucket_kernel(
    const int* __restrict__ ei, const float* __restrict__ ew,
    int* __restrict__ cursor, int2* __restrict__ sorted) {
  int e = blockIdx.x * 256 + threadIdx.x;
  if (e >= NE) return;
  int src = ei[e];
  int dst = ei[NE + e];
  float w = ew[e];
  int pos = atomicAdd(&cursor[dst], 1);
  sorted[pos] = make_int2(src, __float_as_int(w));
}

// ---------------------------------------------------------------------------
// Phase 1d: gather-aggregate. One wave per node; lanes 0-31 even edges,
// lanes 32-63 odd edges; float4 gather per lane; fp32 accumulate; combine
// halves via __shfl_xor; write the row as BF16 (feeds the MFMA GEMM).
// ---------------------------------------------------------------------------
__global__ __launch_bounds__(256) void aggregate_kernel(
    const float* __restrict__ x, const int2* __restrict__ sorted,
    const int* __restrict__ offs, const int* __restrict__ cursor,
    unsigned short* __restrict__ aggr16) {
  int wid = (blockIdx.x * 256 + threadIdx.x) >> 6;   // wave id == node id
  int lane = threadIdx.x & 63;
  int half = lane >> 5;        // 0: even edges, 1: odd edges
  int l32 = lane & 31;         // column group: cols l32*4 .. l32*4+3
  if (wid >= NN) return;
  int s = offs[wid];
  int e = cursor[wid];
  const float4* xp = reinterpret_cast<const float4*>(x);
  float4 acc = make_float4(0.f, 0.f, 0.f, 0.f);
  for (int i = s + half; i < e; i += 2) {
    int2 m = sorted[i];
    float w = __int_as_float(m.y);
    float4 v = xp[(size_t)m.x * 32 + l32];
    acc.x += w * v.x;
    acc.y += w * v.y;
    acc.z += w * v.z;
    acc.w += w * v.w;
  }
  acc.x += __shfl_xor(acc.x, 32, 64);
  acc.y += __shfl_xor(acc.y, 32, 64);
  acc.z += __shfl_xor(acc.z, 32, 64);
  acc.w += __shfl_xor(acc.w, 32, 64);
  if (half == 0) {
    ushort4 o;
    o.x = f2bf(acc.x); o.y = f2bf(acc.y);
    o.z = f2bf(acc.z); o.w = f2bf(acc.w);
    reinterpret_cast<ushort4*>(aggr16)[(size_t)wid * 32 + l32] = o;
  }
}

// ---------------------------------------------------------------------------
// Pack [Wrel; Wroot] (256x128 fp32) into MFMA-B fragment order, bf16.
// Frag (n, ks): lane l, j=0..7 -> B[ks*32 + (l>>4)*8 + j][n*16 + (l&15)].
// Layout: wpack[((n*8 + ks)*64 + l)*8 + j]. One 16B load per frag per lane.
// ---------------------------------------------------------------------------
__global__ __launch_bounds__(256) void pack_w_kernel(
    const float* __restrict__ Wrel, const float* __restrict__ Wroot,
    unsigned short* __restrict__ wpack) {
  int n = blockIdx.x;                 // 0..7
  for (int idx = threadIdx.x; idx < 8 * 64; idx += 256) {
    int ks = idx >> 6;
    int l = idx & 63;
    int srcN = n * 16 + (l & 15);
    short8v o;
    #pragma unroll
    for (int j = 0; j < 8; ++j) {
      int srcK = ks * 32 + ((l >> 4) << 3) + j;
      float v = (srcK < DD) ? Wrel[srcK * DD + srcN]
                            : Wroot[(srcK - DD) * DD + srcN];
      o[j] = (short)f2bf(v);
    }
    *reinterpret_cast<short8v*>(&wpack[(((size_t)(n * 8 + ks)) * 64 + l) * 8]) = o;
  }
}

// ---------------------------------------------------------------------------
// Phase 2: h = [aggr16 | bf16(x)] @ wpack + b_rel via MFMA 16x16x32 bf16.
// Block: 4 waves x 16 rows = 64 rows, N=128 full width, K=256 (8 k-steps).
// A staged in LDS, row stride 264 shorts (+8 pad -> conflict-free b128 reads).
// Fused BN statistics (LDS + global atomics). h written fp32 to d_out.
// ---------------------------------------------------------------------------
__global__ __launch_bounds__(256) void mfma_gemm_bn_stats_kernel(
    const unsigned short* __restrict__ aggr16, const float* __restrict__ x,
    const unsigned short* __restrict__ wpack, const float* __restrict__ brel,
    float* __restrict__ h, float* __restrict__ gsum, float* __restrict__ gsq) {
  __shared__ short Als[64 * 264];   // 33792 B
  __shared__ float s_sum[DD];
  __shared__ float s_sq[DD];

  const int t = threadIdx.x;
  const int row0 = blockIdx.x * 64;

  if (t < DD) { s_sum[t] = 0.f; s_sq[t] = 0.f; }

  // Stage A tile: 64 rows x 32 groups of 8 bf16 (16 B each).
  // g<16: aggr16 row halves; g>=16: x fp32 converted on the fly.
  for (int i = t; i < 64 * 32; i += 256) {
    int r = i >> 5;
    int g = i & 31;
    int grow = row0 + r;
    short8v val = (short8v)0;
    if (grow < NN) {
      if (g < 16) {
        val = *reinterpret_cast<const short8v*>(
            &aggr16[(size_t)grow * DD + g * 8]);
      } else {
        float4 f0 = reinterpret_cast<const float4*>(x)[(size_t)grow * 32 + (g - 16) * 2];
        float4 f1 = reinterpret_cast<const float4*>(x)[(size_t)grow * 32 + (g - 16) * 2 + 1];
        val = pack8(f0, f1);
      }
    }
    *reinterpret_cast<short8v*>(&Als[r * 264 + g * 8]) = val;
  }
  __syncthreads();

  const int w = t >> 6;      // wave 0..3 -> rows [w*16, w*16+16)
  const int l = t & 63;
  const int lm = l & 15;     // A-row (input) / C-col (output) lane index
  const int lq = l >> 4;     // 0..3

  float4v acc[8];
  #pragma unroll
  for (int n = 0; n < 8; ++n) acc[n] = (float4v)0.f;

  const short8v* wp = reinterpret_cast<const short8v*>(wpack);
  #pragma unroll
  for (int ks = 0; ks < 8; ++ks) {
    short8v a = *reinterpret_cast<const short8v*>(
        &Als[(w * 16 + lm) * 264 + (ks * 4 + lq) * 8]);
    #pragma unroll
    for (int n = 0; n < 8; ++n) {
      short8v b = wp[(n * 8 + ks) * 64 + l];
      acc[n] = __builtin_amdgcn_mfma_f32_16x16x32_bf16(a, b, acc[n], 0, 0, 0);
    }
  }

  // Epilogue: + b_rel, store h (fp32), accumulate BN stats.
  #pragma unroll
  for (int n = 0; n < 8; ++n) {
    int col = n * 16 + lm;
    float bv = brel[col];
    float ps = 0.f, pq = 0.f;
    #pragma unroll
    for (int r = 0; r < 4; ++r) {
      int grow = row0 + w * 16 + lq * 4 + r;
      if (grow < NN) {
        float v = acc[n][r] + bv;
        h[(size_t)grow * DD + col] = v;
        ps += v; pq += v * v;
      }
    }
    atomicAdd(&s_sum[col], ps);
    atomicAdd(&s_sq[col], pq);
  }
  __syncthreads();
  if (t < DD) {
    atomicAdd(&gsum[t], s_sum[t]);
    atomicAdd(&gsq[t], s_sq[t]);
  }
}

// ---------------------------------------------------------------------------
// Phase 3: out = relu((h - mean) * rsqrt(var + eps) * gamma + beta) + x
// ---------------------------------------------------------------------------
__global__ __launch_bounds__(256) void bn_relu_res_kernel(
    const float* __restrict__ x, const float* __restrict__ gamma,
    const float* __restrict__ beta, const float* __restrict__ gsum,
    const float* __restrict__ gsq, float* __restrict__ out) {
  __shared__ float sc[DD];
  __shared__ float sh[DD];
  const int t = threadIdx.x;
  if (t < DD) {
    float mean = gsum[t] * (1.f / NN);
    float var = gsq[t] * (1.f / NN) - mean * mean;
    float rstd = rsqrtf(var + BN_EPS);
    float s = gamma[t] * rstd;
    sc[t] = s;
    sh[t] = beta[t] - mean * s;
  }
  __syncthreads();
  const int total4 = NN * DD / 4;
  for (int i = blockIdx.x * 256 + t; i < total4; i += gridDim.x * 256) {
    float4 h4 = reinterpret_cast<const float4*>(out)[i];
    float4 x4 = reinterpret_cast<const float4*>(x)[i];
    int c = (i & 31) << 2;
    float4 o;
    o.x = fmaxf(h4.x * sc[c + 0] + sh[c + 0], 0.f) + x4.x;
    o.y = fmaxf(h4.y * sc[c + 1] + sh[c + 1], 0.f) + x4.y;
    o.z = fmaxf(h4.z * sc[c + 2] + sh[c + 2], 0.f) + x4.z;
    o.w = fmaxf(h4.w * sc[c + 3] + sh[c + 3], 0.f) + x4.w;
    reinterpret_cast<float4*>(out)[i] = o;
  }
}

// ---------------------------------------------------------------------------
extern "C" void kernel_launch(void* const* d_in, const int* in_sizes, int n_in,
                              void* d_out, int out_size, void* d_ws, size_t ws_size,
                              hipStream_t stream) {
  const float* x     = (const float*)d_in[0];
  const int*   ei    = (const int*)d_in[1];
  const float* ew    = (const float*)d_in[2];
  const float* Wrel  = (const float*)d_in[3];
  const float* brel  = (const float*)d_in[4];
  const float* Wroot = (const float*)d_in[5];
  const float* gamma = (const float*)d_in[6];
  const float* beta  = (const float*)d_in[7];
  float* out = (float*)d_out;

  // ws layout: deg[NN] | gsum[DD] | gsq[DD] | offs[NN] | cursor[NN] |
  //            bsum[NB] | bofs[NB] | pad | sorted[NE] int2 |
  //            aggr16[NN*DD] bf16 | wpack[8*8*64*8] bf16     (~39.7 MB)
  int*   deg    = (int*)d_ws;
  float* gsum   = (float*)(deg + NN);
  float* gsq    = gsum + DD;
  int*   offs   = (int*)(gsq + DD);
  int*   cursor = offs + NN;
  int*   bsum   = cursor + NN;
  int*   bofs   = bsum + NB;
  int2*  sorted = (int2*)(bofs + NB + 2);   // 8B-aligned
  unsigned short* aggr16 = (unsigned short*)(sorted + NE);   // 16B-aligned
  unsigned short* wpack  = aggr16 + (size_t)NN * DD;         // 16B-aligned

  // zero: deg + gsum + gsq (contiguous head of ws)
  hipMemsetAsync(d_ws, 0, (size_t)(NN + 2 * DD) * sizeof(int), stream);

  const int eblocks = (NE + 255) / 256;   // 6250
  hist_kernel<<<eblocks, 256, 0, stream>>>(ei, deg);
  scan_part_kernel<<<NB, 256, 0, stream>>>(deg, bsum);
  scan_block_kernel<<<1, 512, 0, stream>>>(bsum, bofs);
  scan_write_kernel<<<NB, 256, 0, stream>>>(deg, bofs, offs, cursor);
  bucket_kernel<<<eblocks, 256, 0, stream>>>(ei, ew, cursor, sorted);
  pack_w_kernel<<<8, 256, 0, stream>>>(Wrel, Wroot, wpack);
  {
    const int blocks = (NN * 64 + 255) / 256;  // 25000, one wave per node
    aggregate_kernel<<<blocks, 256, 0, stream>>>(x, sorted, offs, cursor, aggr16);
  }
  mfma_gemm_bn_stats_kernel<<<MB, 256, 0, stream>>>(
      aggr16, x, wpack, brel, out, gsum, gsq);
  bn_relu_res_kernel<<<2048, 256, 0, stream>>>(x, gamma, beta, gsum, gsq, out);
}

// Round 8
// 519.727 us; speedup vs baseline: 5.7285x; 1.0013x over previous
//
#include <hip/hip_runtime.h>

#define NN 100000
#define NE 1600000
#define DD 128
#define BN_EPS 1e-5f
#define NB 391       // scan blocks: 391*256 = 100096 >= NN
#define MB 1563      // gemm blocks: 1563*64 >= NN

typedef __attribute__((ext_vector_type(8))) short short8v;
typedef __attribute__((ext_vector_type(4))) float float4v;

__device__ inline unsigned short f2bf(float f) {
  unsigned u = __float_as_uint(f);
  return (unsigned short)((u + 0x7FFF + ((u >> 16) & 1)) >> 16);  // RNE
}
__device__ inline short8v pack8(float4 a, float4 b) {
  short8v o;
  o[0] = (short)f2bf(a.x); o[1] = (short)f2bf(a.y);
  o[2] = (short)f2bf(a.z); o[3] = (short)f2bf(a.w);
  o[4] = (short)f2bf(b.x); o[5] = (short)f2bf(b.y);
  o[6] = (short)f2bf(b.z); o[7] = (short)f2bf(b.w);
  return o;
}

// ---------------------------------------------------------------------------
// Phase 0: x (fp32) -> x16 (bf16), one pass. 6250 blocks x 256 thr x 8 elems.
// ---------------------------------------------------------------------------
__global__ __launch_bounds__(256) void x2bf_kernel(
    const float* __restrict__ x, unsigned short* __restrict__ x16) {
  int i = blockIdx.x * 256 + threadIdx.x;       // one short8 per thread
  if (i >= NN * DD / 8) return;
  float4 f0 = reinterpret_cast<const float4*>(x)[(size_t)i * 2];
  float4 f1 = reinterpret_cast<const float4*>(x)[(size_t)i * 2 + 1];
  reinterpret_cast<short8v*>(x16)[i] = pack8(f0, f1);
}

// ---------------------------------------------------------------------------
// Phase 1a: histogram of dst degrees
// ---------------------------------------------------------------------------
__global__ __launch_bounds__(256) void hist_kernel(
    const int* __restrict__ ei, int* __restrict__ deg) {
  int e = blockIdx.x * 256 + threadIdx.x;
  if (e >= NE) return;
  atomicAdd(&deg[ei[NE + e]], 1);
}

// ---------------------------------------------------------------------------
// Phase 1b: device-wide exclusive scan of deg, 3 tiny kernels.
// ---------------------------------------------------------------------------
__global__ __launch_bounds__(256) void scan_part_kernel(
    const int* __restrict__ deg, int* __restrict__ bsum) {
  __shared__ int sc[256];
  int t = threadIdx.x;
  int i = blockIdx.x * 256 + t;
  int v = (i < NN) ? deg[i] : 0;
  sc[t] = v;
  __syncthreads();
  #pragma unroll
  for (int d = 1; d < 256; d <<= 1) {
    int u = (t >= d) ? sc[t - d] : 0;
    __syncthreads();
    sc[t] += u;
    __syncthreads();
  }
  if (t == 255) bsum[blockIdx.x] = sc[255];
}

__global__ __launch_bounds__(512) void scan_block_kernel(
    int* __restrict__ bsum, int* __restrict__ bofs) {
  __shared__ int sc[512];
  int t = threadIdx.x;
  int v = (t < NB) ? bsum[t] : 0;
  sc[t] = v;
  __syncthreads();
  #pragma unroll
  for (int d = 1; d < 512; d <<= 1) {
    int u = (t >= d) ? sc[t - d] : 0;
    __syncthreads();
    sc[t] += u;
    __syncthreads();
  }
  if (t < NB) bofs[t] = sc[t] - v;   // exclusive
}

__global__ __launch_bounds__(256) void scan_write_kernel(
    const int* __restrict__ deg, const int* __restrict__ bofs,
    int* __restrict__ offs, int* __restrict__ cursor) {
  __shared__ int sc[256];
  int t = threadIdx.x;
  int i = blockIdx.x * 256 + t;
  int v = (i < NN) ? deg[i] : 0;
  sc[t] = v;
  __syncthreads();
  #pragma unroll
  for (int d = 1; d < 256; d <<= 1) {
    int u = (t >= d) ? sc[t - d] : 0;
    __syncthreads();
    sc[t] += u;
    __syncthreads();
  }
  if (i < NN) {
    int excl = sc[t] - v + bofs[blockIdx.x];
    offs[i] = excl;
    cursor[i] = excl;
  }
}

// ---------------------------------------------------------------------------
// Phase 1c: bucket edges by dst. 4-byte payload: (src:17b << 15) | bf16(w):15b
// (w >= 0 so the bf16 sign bit is free). Halves the XCD-amplified write-out.
// ---------------------------------------------------------------------------
__global__ __launch_bounds__(256) void bucket_kernel(
    const int* __restrict__ ei, const float* __restrict__ ew,
    int* __restrict__ cursor, unsigned* __restrict__ sorted) {
  int e = blockIdx.x * 256 + threadIdx.x;
  if (e >= NE) return;
  int src = ei[e];
  int dst = ei[NE + e];
  unsigned w15 = f2bf(ew[e]);              // sign bit is 0
  int pos = atomicAdd(&cursor[dst], 1);
  sorted[pos] = ((unsigned)src << 15) | w15;
}

// ---------------------------------------------------------------------------
// Phase 1d (bf16 path): gather-aggregate from x16. One wave per node; lanes
// 0-31 even edges, 32-63 odd edges; 8 B/lane (4 bf16 cols); fp32 accumulate;
// halves combined via __shfl_xor; row written as bf16 for the MFMA GEMM.
// ---------------------------------------------------------------------------
__global__ __launch_bounds__(256) void aggregate16_kernel(
    const unsigned short* __restrict__ x16, const unsigned* __restrict__ sorted,
    const int* __restrict__ offs, const int* __restrict__ cursor,
    unsigned short* __restrict__ aggr16) {
  int wid = (blockIdx.x * 256 + threadIdx.x) >> 6;   // wave id == node id
  int lane = threadIdx.x & 63;
  int half = lane >> 5;
  int l32 = lane & 31;         // cols l32*4 .. l32*4+3
  if (wid >= NN) return;
  int s = offs[wid];
  int e = cursor[wid];
  const uint2* xp = reinterpret_cast<const uint2*>(x16);
  float a0 = 0.f, a1 = 0.f, a2 = 0.f, a3 = 0.f;
  for (int i = s + half; i < e; i += 2) {
    unsigned p = sorted[i];
    float w = __uint_as_float((p & 0x7FFFu) << 16);
    unsigned src = p >> 15;
    uint2 v = xp[(size_t)src * 32 + l32];
    a0 += w * __uint_as_float(v.x << 16);
    a1 += w * __uint_as_float(v.x & 0xFFFF0000u);
    a2 += w * __uint_as_float(v.y << 16);
    a3 += w * __uint_as_float(v.y & 0xFFFF0000u);
  }
  a0 += __shfl_xor(a0, 32, 64);
  a1 += __shfl_xor(a1, 32, 64);
  a2 += __shfl_xor(a2, 32, 64);
  a3 += __shfl_xor(a3, 32, 64);
  if (half == 0) {
    ushort4 o;
    o.x = f2bf(a0); o.y = f2bf(a1); o.z = f2bf(a2); o.w = f2bf(a3);
    reinterpret_cast<ushort4*>(aggr16)[(size_t)wid * 32 + l32] = o;
  }
}

// ---------------------------------------------------------------------------
// Phase 1d (fallback, fp32 gather) — used only if ws_size can't hold x16.
// ---------------------------------------------------------------------------
__global__ __launch_bounds__(256) void aggregate_f32_kernel(
    const float* __restrict__ x, const unsigned* __restrict__ sorted,
    const int* __restrict__ offs, const int* __restrict__ cursor,
    unsigned short* __restrict__ aggr16) {
  int wid = (blockIdx.x * 256 + threadIdx.x) >> 6;
  int lane = threadIdx.x & 63;
  int half = lane >> 5;
  int l32 = lane & 31;
  if (wid >= NN) return;
  int s = offs[wid];
  int e = cursor[wid];
  const float4* xp = reinterpret_cast<const float4*>(x);
  float4 acc = make_float4(0.f, 0.f, 0.f, 0.f);
  for (int i = s + half; i < e; i += 2) {
    unsigned p = sorted[i];
    float w = __uint_as_float((p & 0x7FFFu) << 16);
    unsigned src = p >> 15;
    float4 v = xp[(size_t)src * 32 + l32];
    acc.x += w * v.x; acc.y += w * v.y;
    acc.z += w * v.z; acc.w += w * v.w;
  }
  acc.x += __shfl_xor(acc.x, 32, 64);
  acc.y += __shfl_xor(acc.y, 32, 64);
  acc.z += __shfl_xor(acc.z, 32, 64);
  acc.w += __shfl_xor(acc.w, 32, 64);
  if (half == 0) {
    ushort4 o;
    o.x = f2bf(acc.x); o.y = f2bf(acc.y);
    o.z = f2bf(acc.z); o.w = f2bf(acc.w);
    reinterpret_cast<ushort4*>(aggr16)[(size_t)wid * 32 + l32] = o;
  }
}

// ---------------------------------------------------------------------------
// Pack [Wrel; Wroot] (256x128 fp32) into MFMA-B fragment order, bf16.
// Frag (n, ks): lane l, j=0..7 -> B[ks*32 + (l>>4)*8 + j][n*16 + (l&15)].
// ---------------------------------------------------------------------------
__global__ __launch_bounds__(256) void pack_w_kernel(
    const float* __restrict__ Wrel, const float* __restrict__ Wroot,
    unsigned short* __restrict__ wpack) {
  int n = blockIdx.x;                 // 0..7
  for (int idx = threadIdx.x; idx < 8 * 64; idx += 256) {
    int ks = idx >> 6;
    int l = idx & 63;
    int srcN = n * 16 + (l & 15);
    short8v o;
    #pragma unroll
    for (int j = 0; j < 8; ++j) {
      int srcK = ks * 32 + ((l >> 4) << 3) + j;
      float v = (srcK < DD) ? Wrel[srcK * DD + srcN]
                            : Wroot[(srcK - DD) * DD + srcN];
      o[j] = (short)f2bf(v);
    }
    *reinterpret_cast<short8v*>(&wpack[(((size_t)(n * 8 + ks)) * 64 + l) * 8]) = o;
  }
}

// ---------------------------------------------------------------------------
// Phase 2: h = [aggr16 | bf16(x)] @ wpack + b_rel via MFMA 16x16x32 bf16.
// Block: 4 waves x 16 rows = 64 rows, N=128 full width, K=256 (8 k-steps).
// A staged in LDS, row stride 264 shorts (+8 pad -> conflict-free b128 reads).
// Fused BN statistics (LDS + global atomics). h written fp32 to d_out.
// ---------------------------------------------------------------------------
__global__ __launch_bounds__(256) void mfma_gemm_bn_stats_kernel(
    const unsigned short* __restrict__ aggr16, const float* __restrict__ x,
    const unsigned short* __restrict__ wpack, const float* __restrict__ brel,
    float* __restrict__ h, float* __restrict__ gsum, float* __restrict__ gsq) {
  __shared__ short Als[64 * 264];   // 33792 B
  __shared__ float s_sum[DD];
  __shared__ float s_sq[DD];

  const int t = threadIdx.x;
  const int row0 = blockIdx.x * 64;

  if (t < DD) { s_sum[t] = 0.f; s_sq[t] = 0.f; }

  for (int i = t; i < 64 * 32; i += 256) {
    int r = i >> 5;
    int g = i & 31;
    int grow = row0 + r;
    short8v val = (short8v)0;
    if (grow < NN) {
      if (g < 16) {
        val = *reinterpret_cast<const short8v*>(
            &aggr16[(size_t)grow * DD + g * 8]);
      } else {
        float4 f0 = reinterpret_cast<const float4*>(x)[(size_t)grow * 32 + (g - 16) * 2];
        float4 f1 = reinterpret_cast<const float4*>(x)[(size_t)grow * 32 + (g - 16) * 2 + 1];
        val = pack8(f0, f1);
      }
    }
    *reinterpret_cast<short8v*>(&Als[r * 264 + g * 8]) = val;
  }
  __syncthreads();

  const int w = t >> 6;      // wave 0..3 -> rows [w*16, w*16+16)
  const int l = t & 63;
  const int lm = l & 15;
  const int lq = l >> 4;

  float4v acc[8];
  #pragma unroll
  for (int n = 0; n < 8; ++n) acc[n] = (float4v)0.f;

  const short8v* wp = reinterpret_cast<const short8v*>(wpack);
  #pragma unroll
  for (int ks = 0; ks < 8; ++ks) {
    short8v a = *reinterpret_cast<const short8v*>(
        &Als[(w * 16 + lm) * 264 + (ks * 4 + lq) * 8]);
    #pragma unroll
    for (int n = 0; n < 8; ++n) {
      short8v b = wp[(n * 8 + ks) * 64 + l];
      acc[n] = __builtin_amdgcn_mfma_f32_16x16x32_bf16(a, b, acc[n], 0, 0, 0);
    }
  }

  #pragma unroll
  for (int n = 0; n < 8; ++n) {
    int col = n * 16 + lm;
    float bv = brel[col];
    float ps = 0.f, pq = 0.f;
    #pragma unroll
    for (int r = 0; r < 4; ++r) {
      int grow = row0 + w * 16 + lq * 4 + r;
      if (grow < NN) {
        float v = acc[n][r] + bv;
        h[(size_t)grow * DD + col] = v;
        ps += v; pq += v * v;
      }
    }
    atomicAdd(&s_sum[col], ps);
    atomicAdd(&s_sq[col], pq);
  }
  __syncthreads();
  if (t < DD) {
    atomicAdd(&gsum[t], s_sum[t]);
    atomicAdd(&gsq[t], s_sq[t]);
  }
}

// ---------------------------------------------------------------------------
// Phase 3: out = relu((h - mean) * rsqrt(var + eps) * gamma + beta) + x
// ---------------------------------------------------------------------------
__global__ __launch_bounds__(256) void bn_relu_res_kernel(
    const float* __restrict__ x, const float* __restrict__ gamma,
    const float* __restrict__ beta, const float* __restrict__ gsum,
    const float* __restrict__ gsq, float* __restrict__ out) {
  __shared__ float sc[DD];
  __shared__ float sh[DD];
  const int t = threadIdx.x;
  if (t < DD) {
    float mean = gsum[t] * (1.f / NN);
    float var = gsq[t] * (1.f / NN) - mean * mean;
    float rstd = rsqrtf(var + BN_EPS);
    float s = gamma[t] * rstd;
    sc[t] = s;
    sh[t] = beta[t] - mean * s;
  }
  __syncthreads();
  const int total4 = NN * DD / 4;
  for (int i = blockIdx.x * 256 + t; i < total4; i += gridDim.x * 256) {
    float4 h4 = reinterpret_cast<const float4*>(out)[i];
    float4 x4 = reinterpret_cast<const float4*>(x)[i];
    int c = (i & 31) << 2;
    float4 o;
    o.x = fmaxf(h4.x * sc[c + 0] + sh[c + 0], 0.f) + x4.x;
    o.y = fmaxf(h4.y * sc[c + 1] + sh[c + 1], 0.f) + x4.y;
    o.z = fmaxf(h4.z * sc[c + 2] + sh[c + 2], 0.f) + x4.z;
    o.w = fmaxf(h4.w * sc[c + 3] + sh[c + 3], 0.f) + x4.w;
    reinterpret_cast<float4*>(out)[i] = o;
  }
}

// ---------------------------------------------------------------------------
extern "C" void kernel_launch(void* const* d_in, const int* in_sizes, int n_in,
                              void* d_out, int out_size, void* d_ws, size_t ws_size,
                              hipStream_t stream) {
  const float* x     = (const float*)d_in[0];
  const int*   ei    = (const int*)d_in[1];
  const float* ew    = (const float*)d_in[2];
  const float* Wrel  = (const float*)d_in[3];
  const float* brel  = (const float*)d_in[4];
  const float* Wroot = (const float*)d_in[5];
  const float* gamma = (const float*)d_in[6];
  const float* beta  = (const float*)d_in[7];
  float* out = (float*)d_out;

  // ws layout: deg | gsum | gsq | offs | cursor | bsum | bofs | sorted u32 |
  //            aggr16 bf16 | wpack bf16 | x16 bf16 (optional, ~59 MB total)
  char* p = (char*)d_ws;
  int*   deg    = (int*)p;    p += (size_t)NN * 4;
  float* gsum   = (float*)p;  p += DD * 4;
  float* gsq    = (float*)p;  p += DD * 4;
  int*   offs   = (int*)p;    p += (size_t)NN * 4;
  int*   cursor = (int*)p;    p += (size_t)NN * 4;
  int*   bsum   = (int*)p;    p += NB * 4;
  int*   bofs   = (int*)p;    p += NB * 4;
  p = (char*)(((size_t)p + 15) & ~(size_t)15);
  unsigned* sorted = (unsigned*)p;          p += (size_t)NE * 4;
  unsigned short* aggr16 = (unsigned short*)p; p += (size_t)NN * DD * 2;
  unsigned short* wpack  = (unsigned short*)p; p += (size_t)8 * 8 * 64 * 8 * 2;
  p = (char*)(((size_t)p + 15) & ~(size_t)15);
  unsigned short* x16 = (unsigned short*)p;    p += (size_t)NN * DD * 2;
  const bool use16 = ((size_t)(p - (char*)d_ws) <= ws_size);  // constant per run

  // zero: deg + gsum + gsq (contiguous head of ws)
  hipMemsetAsync(d_ws, 0, (size_t)(NN + 2 * DD) * sizeof(int), stream);

  const int eblocks = (NE + 255) / 256;   // 6250
  hist_kernel<<<eblocks, 256, 0, stream>>>(ei, deg);
  scan_part_kernel<<<NB, 256, 0, stream>>>(deg, bsum);
  scan_block_kernel<<<1, 512, 0, stream>>>(bsum, bofs);
  scan_write_kernel<<<NB, 256, 0, stream>>>(deg, bofs, offs, cursor);
  bucket_kernel<<<eblocks, 256, 0, stream>>>(ei, ew, cursor, sorted);
  pack_w_kernel<<<8, 256, 0, stream>>>(Wrel, Wroot, wpack);
  {
    const int blocks = (NN * 64 + 255) / 256;  // 25000, one wave per node
    if (use16) {
      x2bf_kernel<<<(NN * DD / 8 + 255) / 256, 256, 0, stream>>>(x, x16);
      aggregate16_kernel<<<blocks, 256, 0, stream>>>(x16, sorted, offs, cursor,
                                                     aggr16);
    } else {
      aggregate_f32_kernel<<<blocks, 256, 0, stream>>>(x, sorted, offs, cursor,
                                                       aggr16);
    }
  }
  mfma_gemm_bn_stats_kernel<<<MB, 256, 0, stream>>>(
      aggr16, x, wpack, brel, out, gsum, gsq);
  bn_relu_res_kernel<<<2048, 256, 0, stream>>>(x, gamma, beta, gsum, gsq, out);
}